// Round 4
// baseline (337.180 us; speedup 1.0000x reference)
//
#include <hip/hip_runtime.h>
#include <hip/hip_bf16.h>

// SimpleVSN: B=64, T=512, F=32, H=64. Inputs fp32; OUTPUT fp32 (reference's
// dtype; the bf16-grade threshold is tolerance mode, not output dtype).
//
// Algebraic restructure: never materialize v.
//   U[f,hh,fp] = sum_k W2[f,hh,k]*Wsel[fp, f*64+k]   (device-global, 256KB)
//   c[fp]      = bsel[fp] + sum_d b2flat[d]*Wsel[fp,d]
//   logits[fp] = sum_{f,hh} h[f,hh]*U[f,hh,fp] + c[fp]
//   out[k]     = sum_f w_f * (h_f @ W2[f] + b2[f])   (h recomputed, cheap)
//
// vsn_main: 1 wave = 64 tokens (lane = token); 4 waves/block split the 32
// features 8-per-wave. fbase readfirstlane'd -> all weight addresses
// wave-uniform -> s_load on the scalar pipe; inner loops pure v_fmac.
// Cross-wave reductions via padded LDS (stride 33/65: 2-way = free).
// U/c live in __device__ globals: no d_ws dependence at all.

namespace {
constexpr int F = 32;
constexpr int H = 64;
constexpr int TOK_PER_BLK = 64;
}

__device__ float g_U[F * H * F];   // [f][hh][fp], stride [H*F, F, 1]
__device__ float g_c[F];

__global__ void vsn_pre(const float* __restrict__ W2, const float* __restrict__ b2,
                        const float* __restrict__ Wsel, const float* __restrict__ bsel) {
  if (blockIdx.x < 256) {
    int idx = blockIdx.x * 256 + threadIdx.x;   // (f, hh, fp), fp innermost
    int fp = idx & (F - 1);
    int hh = (idx >> 5) & (H - 1);
    int f  = idx >> 11;
    const float* w2r = W2 + (f * H + hh) * H;         // W2[f,hh,:]
    const float* ser = Wsel + fp * (F * H) + f * H;   // Wsel[fp, f*64 + :]
    float s = 0.f;
    #pragma unroll
    for (int k = 0; k < H; ++k) s = fmaf(w2r[k], ser[k], s);
    g_U[(f * H + hh) * F + fp] = s;
  } else {
    // c[fp] = bsel[fp] + sum_d b2flat[d] * Wsel[fp, d]
    int t = threadIdx.x;
    int fp = t >> 3;        // 0..31
    int part = t & 7;       // 8 partial sums of 256 each
    const float* ser = Wsel + fp * (F * H);
    float s = 0.f;
    for (int d = part * 256; d < part * 256 + 256; ++d) s = fmaf(b2[d], ser[d], s);
    s += __shfl_xor(s, 1);
    s += __shfl_xor(s, 2);
    s += __shfl_xor(s, 4);
    if (part == 0) g_c[fp] = s + bsel[fp];
  }
}

__global__ void __launch_bounds__(256)
vsn_main(const float* __restrict__ x, const float* __restrict__ W1,
         const float* __restrict__ b1, const float* __restrict__ W2,
         const float* __restrict__ b2, float* __restrict__ out) {
  __shared__ float red[4 * 64 * 33];  // logit partials (stride 33); reused as out accum (stride 65)
  __shared__ float wsm[64 * 33];      // softmax weights [tok][f], stride 33

  const int tid  = threadIdx.x;
  const int lane = tid & 63;          // lane = local token
  const int wv   = tid >> 6;
  // Wave-uniform feature base in an SGPR -> weight addresses provably uniform
  const int fbase = __builtin_amdgcn_readfirstlane(wv * 8);
  const int tok  = blockIdx.x * TOK_PER_BLK + lane;
  const float* xrow = x + tok * F;

  // per-lane x values for this wave's 8 features (used by both phases)
  float xv[8];
  #pragma unroll
  for (int i = 0; i < 8; ++i) xv[i] = xrow[fbase + i];

  // ---------- phase 1: logits via fused U ----------
  float lg[32];
  #pragma unroll
  for (int j = 0; j < 32; ++j) lg[j] = (fbase == 0) ? g_c[j] : 0.f;

  #pragma unroll 1
  for (int i = 0; i < 8; ++i) {
    const int f = fbase + i;
    const float xf = xv[i];
    const float* w1p = W1 + f * H;
    const float* b1p = b1 + f * H;
    const float* Up  = g_U + f * (H * F);
    #pragma unroll 2
    for (int hh = 0; hh < H; ++hh) {
      float h = fmaxf(fmaf(xf, w1p[hh], b1p[hh]), 0.f);
      #pragma unroll
      for (int j = 0; j < 32; ++j) lg[j] = fmaf(h, Up[hh * 32 + j], lg[j]);
    }
  }

  #pragma unroll
  for (int j = 0; j < 32; ++j) red[tid * 33 + j] = lg[j];
  __syncthreads();

  // per-lane softmax (wave 0 produces the weights; each lane owns its token)
  if (wv == 0) {
    float fl[32];
    #pragma unroll
    for (int j = 0; j < 32; ++j)
      fl[j] = red[lane * 33 + j] + red[(64 + lane) * 33 + j] +
              red[(128 + lane) * 33 + j] + red[(192 + lane) * 33 + j];
    float m = fl[0];
    #pragma unroll
    for (int j = 1; j < 32; ++j) m = fmaxf(m, fl[j]);
    float z = 0.f;
    #pragma unroll
    for (int j = 0; j < 32; ++j) { fl[j] = __expf(fl[j] - m); z += fl[j]; }
    const float inv = 1.f / z;
    #pragma unroll
    for (int j = 0; j < 32; ++j) wsm[lane * 33 + j] = fl[j] * inv;
  }
  __syncthreads();

  // ---------- phase 2: out[k] = sum_f w_f * (h_f @ W2[f] + b2[f]) ----------
  float acc[64];
  #pragma unroll
  for (int k = 0; k < 64; ++k) acc[k] = 0.f;

  #pragma unroll 1
  for (int i = 0; i < 8; ++i) {
    const int f = fbase + i;
    const float xf = xv[i];
    const float wf = wsm[lane * 33 + f];
    const float* w1p = W1 + f * H;
    const float* b1p = b1 + f * H;
    const float* w2p = W2 + f * (H * H);
    #pragma unroll 1    // 64 uniform W2 floats/iter; unroll 2 would blow the SGPR budget
    for (int hh = 0; hh < H; ++hh) {
      float g = fmaxf(fmaf(xf, w1p[hh], b1p[hh]), 0.f) * wf;
      #pragma unroll
      for (int k = 0; k < 64; ++k) acc[k] = fmaf(g, w2p[hh * H + k], acc[k]);
    }
    #pragma unroll
    for (int k = 0; k < 64; ++k) acc[k] = fmaf(wf, b2[f * H + k], acc[k]);
  }

  __syncthreads();

  // serialized cross-wave accumulation into LDS (stride 65: 2-way = free)
  float* oacc = red;
  for (int turn = 0; turn < 4; ++turn) {
    if (wv == turn) {
      if (turn == 0) {
        #pragma unroll
        for (int k = 0; k < 64; ++k) oacc[lane * 65 + k] = acc[k];
      } else {
        #pragma unroll
        for (int k = 0; k < 64; ++k) oacc[lane * 65 + k] += acc[k];
      }
    }
    __syncthreads();
  }

  // coalesced fp32 store: thread j writes elements {j, j+256, ...}
  float* op = out + blockIdx.x * (TOK_PER_BLK * H);
  #pragma unroll
  for (int e = 0; e < 16; ++e) {
    int flat = e * 256 + tid;
    op[flat] = oacc[(flat >> 6) * 65 + (flat & 63)];
  }
}

extern "C" void kernel_launch(void* const* d_in, const int* in_sizes, int n_in,
                              void* d_out, int out_size, void* d_ws, size_t ws_size,
                              hipStream_t stream) {
  (void)in_sizes; (void)n_in; (void)out_size; (void)d_ws; (void)ws_size;
  const float* x    = (const float*)d_in[0];
  const float* W1   = (const float*)d_in[1];
  const float* b1   = (const float*)d_in[2];
  const float* W2   = (const float*)d_in[3];
  const float* b2   = (const float*)d_in[4];
  const float* Wsel = (const float*)d_in[5];
  const float* bsel = (const float*)d_in[6];
  float* out = (float*)d_out;

  vsn_pre<<<257, 256, 0, stream>>>(W2, b2, Wsel, bsel);
  vsn_main<<<512, 256, 0, stream>>>(x, W1, b1, W2, b2, out);
}